// Round 17
// baseline (233.987 us; speedup 1.0000x reference)
//
#include <hip/hip_runtime.h>
#include <hip/hip_bf16.h>

#define HID 1024
#define INTER 4096
#define NE 8
#define NTOK 2048
#define MAXROWS 5120   // 4096 pairs + 8*127 pad, rounded up

typedef __attribute__((ext_vector_type(8))) short short8v;
typedef __attribute__((ext_vector_type(4))) short short4v;
typedef __attribute__((ext_vector_type(4))) float f32x4;

__device__ __forceinline__ unsigned short f2bf(float f) {
  unsigned int u = __builtin_bit_cast(unsigned int, f);
  u = (u + 0x7FFFu + ((u >> 16) & 1u)) >> 16;
  return (unsigned short)u;
}
__device__ __forceinline__ float bf2f(unsigned short s) {
  unsigned int u = ((unsigned int)s) << 16;
  return __builtin_bit_cast(float, u);
}

typedef const __attribute__((address_space(1))) unsigned int* gas_t;
typedef __attribute__((address_space(3))) unsigned int* las_t;
__device__ __forceinline__ void gld16(const unsigned short* g, unsigned short* l) {
  __builtin_amdgcn_global_load_lds((gas_t)(const void*)g, (las_t)(void*)l, 16, 0, 0);
}

// ------- 256-thread 64x64 transpose tile (used by prep for W1) -------
__device__ __forceinline__ void tconv_tile(const float* __restrict__ in,
                                           unsigned short* __restrict__ out,
                                           int R, int C, int bx, int by, int z,
                                           float* __restrict__ t) {
  const int r0 = by * 64, c0 = bx * 64;
  const int tr = threadIdx.x / 16;
  const int tc = (threadIdx.x % 16) * 4;
  const float* ip = in + ((size_t)z * R + r0) * (size_t)C + c0;
#pragma unroll
  for (int p = 0; p < 4; ++p) {
    f32x4 v = __builtin_nontemporal_load((const f32x4*)&ip[(size_t)(p * 16 + tr) * C + tc]);
    t[(p * 16 + tr) * 65 + tc + 0] = v[0];
    t[(p * 16 + tr) * 65 + tc + 1] = v[1];
    t[(p * 16 + tr) * 65 + tc + 2] = v[2];
    t[(p * 16 + tr) * 65 + tc + 3] = v[3];
  }
  __syncthreads();
  unsigned short* op = out + ((size_t)z * C + c0) * (size_t)R + r0;
#pragma unroll
  for (int p = 0; p < 4; ++p) {
    int c = p * 16 + tr;
    unsigned int a0 = (unsigned int)f2bf(t[(tc + 0) * 65 + c]) |
                      ((unsigned int)f2bf(t[(tc + 1) * 65 + c]) << 16);
    unsigned int a1 = (unsigned int)f2bf(t[(tc + 2) * 65 + c]) |
                      ((unsigned int)f2bf(t[(tc + 3) * 65 + c]) << 16);
    uint2 val; val.x = a0; val.y = a1;
    *(uint2*)&op[(size_t)c * R + tc] = val;
  }
}

// ------- wave-private 64(i) x 32(h) transpose of W2 -> w2t (no barriers) -------
__device__ __forceinline__ void wave_tconv2(const float* __restrict__ in,
                                            unsigned short* __restrict__ out,
                                            int gidx, float* __restrict__ sc, int lane) {
  const int e = gidx >> 11;                 // 2048 tiles per expert
  const int r = gidx & 2047;
  const int i0 = (r >> 5) * 64, h0 = (r & 31) * 32;
  const float* ip = in + ((size_t)e * INTER + i0) * HID + h0;
  f32x4 v[8];
#pragma unroll
  for (int p = 0; p < 8; ++p)
    v[p] = __builtin_nontemporal_load(
        (const f32x4*)&ip[(size_t)(p * 8 + (lane >> 3)) * HID + (lane & 7) * 4]);
#pragma unroll
  for (int p = 0; p < 8; ++p) {
    const int row = p * 8 + (lane >> 3), col = (lane & 7) * 4;
#pragma unroll
    for (int j = 0; j < 4; ++j) sc[row * 37 + col + j] = v[p][j];
  }
  asm volatile("s_waitcnt lgkmcnt(0)" ::: "memory");
  __builtin_amdgcn_sched_barrier(0);
  unsigned short* op = out + ((size_t)e * HID + h0) * INTER + i0;
#pragma unroll
  for (int p = 0; p < 4; ++p) {
    const int c = p * 8 + (lane >> 3);
    const int r8 = (lane & 7) * 8;
    uint4 w;
    unsigned int* wp = (unsigned int*)&w;
#pragma unroll
    for (int j = 0; j < 4; ++j) {
      unsigned int lo = f2bf(sc[(r8 + 2 * j) * 37 + c]);
      unsigned int hi = f2bf(sc[(r8 + 2 * j + 1) * 37 + c]);
      wp[j] = lo | (hi << 16);
    }
    *(uint4*)&op[(size_t)c * INTER + r8] = w;
  }
}

// ---------------- prep: convx (2048 blocks) + tconv1 (8192) + gating (2048) ----------------
__global__ __launch_bounds__(256) void prep_kernel(const float* __restrict__ x,
                                                   const float* __restrict__ W1,
                                                   const float* __restrict__ wg,
                                                   unsigned short* __restrict__ xb,
                                                   unsigned short* __restrict__ w1t,
                                                   int* __restrict__ tok_e,
                                                   float* __restrict__ tok_w) {
  __shared__ float sh[64 * 65];
  int bid = blockIdx.x;
  if (bid < 2048) {   // ---- convx: x fp32 -> bf16 ----
    size_t i = (size_t)bid * 256 + threadIdx.x;
    f32x4 v = *(const f32x4*)&x[i * 4];
    uint2 r;
    r.x = (unsigned int)f2bf(v[0]) | ((unsigned int)f2bf(v[1]) << 16);
    r.y = (unsigned int)f2bf(v[2]) | ((unsigned int)f2bf(v[3]) << 16);
    *(uint2*)&xb[i * 4] = r;
    return;
  }
  bid -= 2048;
  if (bid < 8192) {   // ---- tconv1: W1 [E][H][I] -> w1t [E][I][H] ----
    tconv_tile(W1, w1t, HID, INTER, bid % 64, (bid / 64) % 16, bid / 1024, sh);
    return;
  }
  bid -= 8192;
  {   // ---- gating for token t = bid ----
    const int t = bid;
    float acc[NE];
#pragma unroll
    for (int e = 0; e < NE; ++e) acc[e] = 0.f;
    for (int k = threadIdx.x; k < HID; k += 256) {
      float xv = x[(size_t)t * HID + k];
#pragma unroll
      for (int e = 0; e < NE; ++e) acc[e] += xv * wg[e * HID + k];
    }
#pragma unroll
    for (int e = 0; e < NE; ++e) {
#pragma unroll
      for (int off = 32; off >= 1; off >>= 1) acc[e] += __shfl_xor(acc[e], off, 64);
    }
    float* red = sh;   // [4][NE]
    const int wave = threadIdx.x >> 6, lane = threadIdx.x & 63;
    if (lane == 0) {
#pragma unroll
      for (int e = 0; e < NE; ++e) red[wave * NE + e] = acc[e];
    }
    __syncthreads();
    if (threadIdx.x == 0) {
      float l[NE];
#pragma unroll
      for (int e = 0; e < NE; ++e)
        l[e] = red[0 * NE + e] + red[1 * NE + e] + red[2 * NE + e] + red[3 * NE + e];
      int i0 = 0;
#pragma unroll
      for (int e = 1; e < NE; ++e) if (l[e] > l[i0]) i0 = e;
      int i1 = -1;
#pragma unroll
      for (int e = 0; e < NE; ++e) {
        if (e == i0) continue;
        if (i1 < 0 || l[e] > l[i1]) i1 = e;
      }
      float e1 = __expf(l[i1] - l[i0]);
      float w0 = 1.f / (1.f + e1);
      tok_e[t * 2 + 0] = i0;
      tok_e[t * 2 + 1] = i1;
      tok_w[t * 2 + 0] = w0;
      tok_w[t * 2 + 1] = 1.f - w0;
    }
  }
}

// ---------------- routing: per-expert compaction (deterministic, single block) ----------------
__global__ __launch_bounds__(512) void routing_kernel(const int* __restrict__ tok_e,
                                                      int* __restrict__ list_tok,
                                                      int* __restrict__ tok_gslot,
                                                      int* __restrict__ offs_out) {
  __shared__ int cnts[NE];
  __shared__ int offs_s[NE + 1];
  const int e = threadIdx.x >> 6, lane = threadIdx.x & 63;
  int c = 0;
  for (int base = 0; base < NTOK; base += 64) {
    int tok = base + lane;
    int e0 = tok_e[tok * 2], e1 = tok_e[tok * 2 + 1];
    bool m = (e0 == e) || (e1 == e);
    unsigned long long mask = __ballot(m);
    c += __popcll(mask);
  }
  if (lane == 0) cnts[e] = c;
  __syncthreads();
  if (threadIdx.x == 0) {
    int o = 0;
    for (int i = 0; i < NE; ++i) { offs_s[i] = o; o += (cnts[i] + 127) & ~127; }
    offs_s[NE] = o;
    for (int i = 0; i <= NE; ++i) offs_out[i] = offs_s[i];
  }
  __syncthreads();
  const int off = offs_s[e];
  int run = 0;
  for (int base = 0; base < NTOK; base += 64) {
    int tok = base + lane;
    int e0 = tok_e[tok * 2], e1 = tok_e[tok * 2 + 1];
    bool m = (e0 == e) || (e1 == e);
    unsigned long long mask = __ballot(m);
    int pos = run + __popcll(mask & ((1ull << lane) - 1ull));
    if (m) {
      int gs = off + pos;
      list_tok[gs] = tok;
      tok_gslot[tok * 2 + ((e0 == e) ? 0 : 1)] = gs;
    }
    run += __popcll(mask);
  }
  const int cnt = cnts[e];
  const int padded = (cnt + 127) & ~127;
  for (int p = cnt + lane; p < padded; p += 64) list_tok[off + p] = 0;
}

// ---------------- grouped GEMM: 128x128 tile, BK=32, ring-3 LDS, counted vmcnt ----------------
// Round-8 verified core (chunk-XOR swizzle, 0 bank conflicts). MERGE=1: grid is 21-stride
// interleaved -- bid%21<5 -> GEMM block (5/21 = 1280), else wave-tconv2 filler (16/21 =
// 4096). Uniform interleave spreads the dead 134MB fp32 W2 stream across the dispatch so
// it doesn't evict h/w2t at the END (round-14 tail-heavy pollution, GEMM2 92us vs 81).
// FIRST: out = bf16 h with bias+GELU; else: out = bf16 partials[ks][row][col] (no bias).
template <int KTOT, int NTOT, bool FIRST, int NSPLIT, bool MERGE>
__global__ __launch_bounds__(256, 3) void moe_gemm(const unsigned short* __restrict__ Abase,
                                                   const unsigned short* __restrict__ Bbase,
                                                   const float* __restrict__ bias,
                                                   const int* __restrict__ list_tok,
                                                   const int* __restrict__ offs,
                                                   void* __restrict__ outp,
                                                   const float* __restrict__ W2f,
                                                   unsigned short* __restrict__ w2t) {
  constexpr int KS = KTOT / NSPLIT;   // K elems per slice
  constexpr int NT = KS / 32;         // K-steps (BK=32)
  constexpr int nM = MAXROWS / 128;
  constexpr int nN = NTOT / 128;
  constexpr int NWG_GEMM = nN * nM * NSPLIT;
  // ring of 3 slots, each: A[128][32] + B[128][32] bf16 = 16KB -> 48KB total
  __shared__ __align__(16) unsigned short lds[3][2][4096];

  const int tid = threadIdx.x;
  const int wave = tid >> 6, lane = tid & 63;

  int wg;
  if (MERGE) {
    const int r = (int)blockIdx.x % 21;
    const int grp = (int)blockIdx.x / 21;
    if (r >= 5) {
      // filler: W2 [E][I][H] -> w2t [E][H][I]; 4 wave-tiles per block
      const int fidx = grp * 16 + (r - 5);          // 0..4095
      wave_tconv2(W2f, w2t, fidx * 4 + wave,
                  (float*)&lds[0][0][0] + wave * (64 * 37), lane);
      return;
    }
    wg = grp * 5 + r;                               // 0..1279 bijective
  } else {
    wg = (int)blockIdx.x;
  }
  wg = (wg & 7) * (NWG_GEMM >> 3) + (wg >> 3);   // bijective XCD swizzle (NWG_GEMM % 8 == 0)
  const int ks = (NSPLIT > 1) ? (wg / (nM * nN)) : 0;
  const int rem = wg % (nM * nN);
  const int mt = rem % nM;                  // m fastest: neighbors share B panel in L2
  const int nt = rem / nM;
  const int grow0 = mt * 128;
  if (grow0 >= offs[NE]) return;
  int e = 0;
#pragma unroll
  for (int i = 1; i < NE; ++i) if (grow0 >= offs[i]) e = i;
  const int n0 = nt * 128;
  const int k0 = ks * KS;

  // --- staging sources: thread covers rows tid/4 + {0,64}; source chunk pre-swizzled ---
  const int srow = tid >> 2;
  const int skc = (((tid & 3) ^ ((srow >> 1) & 3)) * 8);  // chunk XOR swizzle, shorts
  const unsigned short* ag[2];
  const unsigned short* bg[2];
#pragma unroll
  for (int j = 0; j < 2; ++j) {
    const int row = srow + j * 64;   // (row>>1)&3 identical for j=0,1 (bit6 untouched)
    size_t arow;
    if (FIRST) arow = (size_t)list_tok[grow0 + row] * KTOT;
    else       arow = (size_t)(grow0 + row) * KTOT;
    ag[j] = Abase + arow + k0 + skc;
    bg[j] = Bbase + (size_t)e * NTOT * KTOT + (size_t)(n0 + row) * KTOT + k0 + skc;
  }
  // gld16 LDS dest must be WAVE-UNIFORM base (HW adds lane*16B)
  const int wbase = wave * 512;  // shorts: wave*1024B

  // --- fragment read offsets (shorts), swizzle folded in ---
  const int wm = wave >> 1, wn = wave & 1;
  const int fr = lane & 15;
  const int q = lane >> 4;       // 16B chunk index within the 64B row
  int aoff[4], boff[4];
#pragma unroll
  for (int m = 0; m < 4; ++m) {
    const int row = wm * 64 + m * 16 + fr;
    aoff[m] = row * 32 + ((q ^ ((row >> 1) & 3)) * 8);
  }
#pragma unroll
  for (int n = 0; n < 4; ++n) {
    const int row = wn * 64 + n * 16 + fr;
    boff[n] = row * 32 + ((q ^ ((row >> 1) & 3)) * 8);
  }

  f32x4 acc[4][4] = {};

#define STAGE(S, SLOT)                                             \
  {                                                                \
    gld16(ag[0] + (S) * 32, &lds[SLOT][0][wbase]);                 \
    gld16(ag[1] + (S) * 32, &lds[SLOT][0][wbase + 2048]);          \
    gld16(bg[0] + (S) * 32, &lds[SLOT][1][wbase]);                 \
    gld16(bg[1] + (S) * 32, &lds[SLOT][1][wbase + 2048]);          \
  }

#define KITER(S, SL, DO_STAGE, VMSTR)                                 \
  {                                                                   \
    asm volatile("s_waitcnt vmcnt(" VMSTR ")" ::: "memory");          \
    asm volatile("s_barrier" ::: "memory");                           \
    const unsigned short* A = &lds[SL][0][0];                         \
    const unsigned short* B = &lds[SL][1][0];                         \
    short8v af[4], bf[4];                                             \
    _Pragma("unroll")                                                 \
    for (int m = 0; m < 4; ++m) af[m] = *(const short8v*)&A[aoff[m]]; \
    _Pragma("unroll")                                                 \
    for (int n = 0; n < 4; ++n) bf[n] = *(const short8v*)&B[boff[n]]; \
    if (DO_STAGE) {                                                   \
      int s2 = (SL) + 2; if (s2 >= 3) s2 -= 3;                        \
      STAGE((S) + 2, s2);                                             \
    }                                                                 \
    __builtin_amdgcn_s_setprio(1);                                    \
    _Pragma("unroll")                                                 \
    for (int n = 0; n < 4; ++n)                                       \
      _Pragma("unroll")                                               \
      for (int m = 0; m < 4; ++m)                                     \
        acc[m][n] = __builtin_amdgcn_mfma_f32_16x16x32_bf16(af[m], bf[n], acc[m][n], 0, 0, 0); \
    __builtin_amdgcn_s_setprio(0);                                    \
  }

  // prologue: stage steps 0,1 into slots 0,1 (8 loads outstanding)
  STAGE(0, 0);
  STAGE(1, 1);

  int sl = 0;
  for (int s = 0; s < NT - 2; ++s) {
    KITER(s, sl, true, "4");
    sl = sl + 1; if (sl >= 3) sl = 0;
  }
  KITER(NT - 2, sl, false, "4");
  sl = sl + 1; if (sl >= 3) sl = 0;
  KITER(NT - 1, sl, false, "0");

#undef KITER
#undef STAGE

  const int r4 = lane >> 4;
#pragma unroll
  for (int m = 0; m < 4; ++m) {
#pragma unroll
    for (int n = 0; n < 4; ++n) {
      const int gcol = n0 + wn * 64 + n * 16 + fr;
      float bv = 0.f;
      if (FIRST) bv = bias[e * NTOT + gcol];
#pragma unroll
      for (int r = 0; r < 4; ++r) {
        const int grow = grow0 + wm * 64 + m * 16 + r4 * 4 + r;
        float v = acc[m][n][r] + bv;
        if (FIRST) {
          v = 0.5f * v * (1.0f + erff(v * 0.70710678118654752f));
          ((unsigned short*)outp)[(size_t)grow * NTOT + gcol] = f2bf(v);
        } else {
          // bf16 partial (no bias; reduced in combine)
          ((unsigned short*)outp)[((size_t)ks * MAXROWS + grow) * NTOT + gcol] = f2bf(v);
        }
      }
    }
  }
}

// -------- combine: y[t] = w0*(sum_ks p16[ks][gs0]+b2[e0]) + w1*(...)  (4 bf16 slices) --------
template <int NSPLIT>
__global__ __launch_bounds__(256) void combine_kernel(const unsigned short* __restrict__ part,
                                                      const int* __restrict__ tok_gslot,
                                                      const int* __restrict__ tok_e,
                                                      const float* __restrict__ tok_w,
                                                      const float* __restrict__ b2,
                                                      float* __restrict__ y) {
  const int t = blockIdx.x;
  const int c = threadIdx.x * 4;
  const int gs0 = tok_gslot[t * 2 + 0], gs1 = tok_gslot[t * 2 + 1];
  const int e0 = tok_e[t * 2 + 0], e1 = tok_e[t * 2 + 1];
  const float w0 = tok_w[t * 2 + 0], w1 = tok_w[t * 2 + 1];
  float s0[4] = {0.f, 0.f, 0.f, 0.f}, s1[4] = {0.f, 0.f, 0.f, 0.f};
#pragma unroll
  for (int ks = 0; ks < NSPLIT; ++ks) {
    short4v p0 = *(const short4v*)&part[((size_t)ks * MAXROWS + gs0) * HID + c];
    short4v p1 = *(const short4v*)&part[((size_t)ks * MAXROWS + gs1) * HID + c];
#pragma unroll
    for (int i = 0; i < 4; ++i) {
      s0[i] += bf2f((unsigned short)p0[i]);
      s1[i] += bf2f((unsigned short)p1[i]);
    }
  }
  f32x4 bb0 = *(const f32x4*)&b2[e0 * HID + c];
  f32x4 bb1 = *(const f32x4*)&b2[e1 * HID + c];
  f32x4 r;
#pragma unroll
  for (int i = 0; i < 4; ++i)
    r[i] = w0 * (s0[i] + bb0[i]) + w1 * (s1[i] + bb1[i]);
  *(f32x4*)&y[(size_t)t * HID + c] = r;
}

extern "C" void kernel_launch(void* const* d_in, const int* in_sizes, int n_in,
                              void* d_out, int out_size, void* d_ws, size_t ws_size,
                              hipStream_t stream) {
  const float* x  = (const float*)d_in[0];
  const float* wg = (const float*)d_in[1];
  const float* W1 = (const float*)d_in[2];
  const float* b1 = (const float*)d_in[3];
  const float* W2 = (const float*)d_in[4];
  const float* b2 = (const float*)d_in[5];
  float* y = (float*)d_out;

  unsigned char* ws = (unsigned char*)d_ws;
  size_t off = 0;
  // w1t (live prep->gemm1) aliases part (bf16, 4 slices x 10.5MB = 42MB, live gemm2->combine)
  unsigned short* w1t  = (unsigned short*)(ws + off);
  unsigned short* part = (unsigned short*)(ws + off); off += (size_t)NE * HID * INTER * 2;  // 67MB
  unsigned short* w2t  = (unsigned short*)(ws + off); off += (size_t)NE * INTER * HID * 2;  // 67MB
  unsigned short* xb   = (unsigned short*)(ws + off); off += (size_t)NTOK * HID * 2;        // 4MB
  unsigned short* h    = (unsigned short*)(ws + off); off += (size_t)MAXROWS * INTER * 2;   // 42MB
  int* tok_e           = (int*)(ws + off);            off += NTOK * 2 * 4;
  float* tok_w         = (float*)(ws + off);          off += NTOK * 2 * 4;
  int* tok_gslot       = (int*)(ws + off);            off += NTOK * 2 * 4;
  int* list_tok        = (int*)(ws + off);            off += MAXROWS * 4;
  int* offs            = (int*)(ws + off);            off += 64;
  (void)ws_size; (void)in_sizes; (void)n_in; (void)out_size;

  // prep: convx (2048) + tconv1 (8192) + gating (2048) -- all independent
  prep_kernel<<<2048 + 8192 + 2048, 256, 0, stream>>>(x, W1, wg, xb, w1t, tok_e, tok_w);
  routing_kernel<<<1, 512, 0, stream>>>(tok_e, list_tok, tok_gslot, offs);
  // merged dispatch: 21-stride interleave of 1280 GEMM1 blocks + 4096 wave-tconv2 fillers
  moe_gemm<HID, INTER, true, 1, true>
      <<<21 * 256, 256, 0, stream>>>(
          xb, w1t, b1, list_tok, offs, (void*)h, W2, w2t);
  moe_gemm<INTER, HID, false, 4, false>
      <<<(HID / 128) * (MAXROWS / 128) * 4, 256, 0, stream>>>(
          h, w2t, b2, list_tok, offs, (void*)part, nullptr, nullptr);
  combine_kernel<4><<<NTOK, 256, 0, stream>>>(part, tok_gslot, tok_e, tok_w, b2, y);
}

// Round 18
// 213.983 us; speedup vs baseline: 1.0935x; 1.0935x over previous
//
#include <hip/hip_runtime.h>
#include <hip/hip_bf16.h>

#define HID 1024
#define INTER 4096
#define NE 8
#define NTOK 2048
#define MAXROWS 5120   // 4096 pairs + 8*127 pad, rounded up

typedef __attribute__((ext_vector_type(8))) short short8v;
typedef __attribute__((ext_vector_type(4))) short short4v;
typedef __attribute__((ext_vector_type(4))) float f32x4;

__device__ __forceinline__ unsigned short f2bf(float f) {
  unsigned int u = __builtin_bit_cast(unsigned int, f);
  u = (u + 0x7FFFu + ((u >> 16) & 1u)) >> 16;
  return (unsigned short)u;
}
__device__ __forceinline__ float bf2f(unsigned short s) {
  unsigned int u = ((unsigned int)s) << 16;
  return __builtin_bit_cast(float, u);
}

typedef const __attribute__((address_space(1))) unsigned int* gas_t;
typedef __attribute__((address_space(3))) unsigned int* las_t;
__device__ __forceinline__ void gld16(const unsigned short* g, unsigned short* l) {
  __builtin_amdgcn_global_load_lds((gas_t)(const void*)g, (las_t)(void*)l, 16, 0, 0);
}

// ------- 256-thread 64x64 transpose tile (used by prep for W1) -------
__device__ __forceinline__ void tconv_tile(const float* __restrict__ in,
                                           unsigned short* __restrict__ out,
                                           int R, int C, int bx, int by, int z,
                                           float* __restrict__ t) {
  const int r0 = by * 64, c0 = bx * 64;
  const int tr = threadIdx.x / 16;
  const int tc = (threadIdx.x % 16) * 4;
  const float* ip = in + ((size_t)z * R + r0) * (size_t)C + c0;
#pragma unroll
  for (int p = 0; p < 4; ++p) {
    f32x4 v = __builtin_nontemporal_load((const f32x4*)&ip[(size_t)(p * 16 + tr) * C + tc]);
    t[(p * 16 + tr) * 65 + tc + 0] = v[0];
    t[(p * 16 + tr) * 65 + tc + 1] = v[1];
    t[(p * 16 + tr) * 65 + tc + 2] = v[2];
    t[(p * 16 + tr) * 65 + tc + 3] = v[3];
  }
  __syncthreads();
  unsigned short* op = out + ((size_t)z * C + c0) * (size_t)R + r0;
#pragma unroll
  for (int p = 0; p < 4; ++p) {
    int c = p * 16 + tr;
    unsigned int a0 = (unsigned int)f2bf(t[(tc + 0) * 65 + c]) |
                      ((unsigned int)f2bf(t[(tc + 1) * 65 + c]) << 16);
    unsigned int a1 = (unsigned int)f2bf(t[(tc + 2) * 65 + c]) |
                      ((unsigned int)f2bf(t[(tc + 3) * 65 + c]) << 16);
    uint2 val; val.x = a0; val.y = a1;
    *(uint2*)&op[(size_t)c * R + tc] = val;
  }
}

// ------- wave-private 64(i) x 32(h) transpose of W2 -> w2t (no barriers) -------
__device__ __forceinline__ void wave_tconv2(const float* __restrict__ in,
                                            unsigned short* __restrict__ out,
                                            int gidx, float* __restrict__ sc, int lane) {
  const int e = gidx >> 11;                 // 2048 tiles per expert
  const int r = gidx & 2047;
  const int i0 = (r >> 5) * 64, h0 = (r & 31) * 32;
  const float* ip = in + ((size_t)e * INTER + i0) * HID + h0;
  f32x4 v[8];
#pragma unroll
  for (int p = 0; p < 8; ++p)
    v[p] = __builtin_nontemporal_load(
        (const f32x4*)&ip[(size_t)(p * 8 + (lane >> 3)) * HID + (lane & 7) * 4]);
#pragma unroll
  for (int p = 0; p < 8; ++p) {
    const int row = p * 8 + (lane >> 3), col = (lane & 7) * 4;
#pragma unroll
    for (int j = 0; j < 4; ++j) sc[row * 37 + col + j] = v[p][j];
  }
  asm volatile("s_waitcnt lgkmcnt(0)" ::: "memory");
  __builtin_amdgcn_sched_barrier(0);
  unsigned short* op = out + ((size_t)e * HID + h0) * INTER + i0;
#pragma unroll
  for (int p = 0; p < 4; ++p) {
    const int c = p * 8 + (lane >> 3);
    const int r8 = (lane & 7) * 8;
    uint4 w;
    unsigned int* wp = (unsigned int*)&w;
#pragma unroll
    for (int j = 0; j < 4; ++j) {
      unsigned int lo = f2bf(sc[(r8 + 2 * j) * 37 + c]);
      unsigned int hi = f2bf(sc[(r8 + 2 * j + 1) * 37 + c]);
      wp[j] = lo | (hi << 16);
    }
    *(uint4*)&op[(size_t)c * INTER + r8] = w;
  }
}

// ---------------- prep: convx (2048 blocks) + tconv1 (8192) + gating (2048) ----------------
__global__ __launch_bounds__(256) void prep_kernel(const float* __restrict__ x,
                                                   const float* __restrict__ W1,
                                                   const float* __restrict__ wg,
                                                   unsigned short* __restrict__ xb,
                                                   unsigned short* __restrict__ w1t,
                                                   int* __restrict__ tok_e,
                                                   float* __restrict__ tok_w) {
  __shared__ float sh[64 * 65];
  int bid = blockIdx.x;
  if (bid < 2048) {   // ---- convx: x fp32 -> bf16 ----
    size_t i = (size_t)bid * 256 + threadIdx.x;
    f32x4 v = *(const f32x4*)&x[i * 4];
    uint2 r;
    r.x = (unsigned int)f2bf(v[0]) | ((unsigned int)f2bf(v[1]) << 16);
    r.y = (unsigned int)f2bf(v[2]) | ((unsigned int)f2bf(v[3]) << 16);
    *(uint2*)&xb[i * 4] = r;
    return;
  }
  bid -= 2048;
  if (bid < 8192) {   // ---- tconv1: W1 [E][H][I] -> w1t [E][I][H] ----
    tconv_tile(W1, w1t, HID, INTER, bid % 64, (bid / 64) % 16, bid / 1024, sh);
    return;
  }
  bid -= 8192;
  {   // ---- gating for token t = bid ----
    const int t = bid;
    float acc[NE];
#pragma unroll
    for (int e = 0; e < NE; ++e) acc[e] = 0.f;
    for (int k = threadIdx.x; k < HID; k += 256) {
      float xv = x[(size_t)t * HID + k];
#pragma unroll
      for (int e = 0; e < NE; ++e) acc[e] += xv * wg[e * HID + k];
    }
#pragma unroll
    for (int e = 0; e < NE; ++e) {
#pragma unroll
      for (int off = 32; off >= 1; off >>= 1) acc[e] += __shfl_xor(acc[e], off, 64);
    }
    float* red = sh;   // [4][NE]
    const int wave = threadIdx.x >> 6, lane = threadIdx.x & 63;
    if (lane == 0) {
#pragma unroll
      for (int e = 0; e < NE; ++e) red[wave * NE + e] = acc[e];
    }
    __syncthreads();
    if (threadIdx.x == 0) {
      float l[NE];
#pragma unroll
      for (int e = 0; e < NE; ++e)
        l[e] = red[0 * NE + e] + red[1 * NE + e] + red[2 * NE + e] + red[3 * NE + e];
      int i0 = 0;
#pragma unroll
      for (int e = 1; e < NE; ++e) if (l[e] > l[i0]) i0 = e;
      int i1 = -1;
#pragma unroll
      for (int e = 0; e < NE; ++e) {
        if (e == i0) continue;
        if (i1 < 0 || l[e] > l[i1]) i1 = e;
      }
      float e1 = __expf(l[i1] - l[i0]);
      float w0 = 1.f / (1.f + e1);
      tok_e[t * 2 + 0] = i0;
      tok_e[t * 2 + 1] = i1;
      tok_w[t * 2 + 0] = w0;
      tok_w[t * 2 + 1] = 1.f - w0;
    }
  }
}

// ---------------- routing: per-expert compaction (deterministic, single block) ----------------
__global__ __launch_bounds__(512) void routing_kernel(const int* __restrict__ tok_e,
                                                      int* __restrict__ list_tok,
                                                      int* __restrict__ tok_gslot,
                                                      int* __restrict__ offs_out) {
  __shared__ int cnts[NE];
  __shared__ int offs_s[NE + 1];
  const int e = threadIdx.x >> 6, lane = threadIdx.x & 63;
  int c = 0;
  for (int base = 0; base < NTOK; base += 64) {
    int tok = base + lane;
    int e0 = tok_e[tok * 2], e1 = tok_e[tok * 2 + 1];
    bool m = (e0 == e) || (e1 == e);
    unsigned long long mask = __ballot(m);
    c += __popcll(mask);
  }
  if (lane == 0) cnts[e] = c;
  __syncthreads();
  if (threadIdx.x == 0) {
    int o = 0;
    for (int i = 0; i < NE; ++i) { offs_s[i] = o; o += (cnts[i] + 127) & ~127; }
    offs_s[NE] = o;
    for (int i = 0; i <= NE; ++i) offs_out[i] = offs_s[i];
  }
  __syncthreads();
  const int off = offs_s[e];
  int run = 0;
  for (int base = 0; base < NTOK; base += 64) {
    int tok = base + lane;
    int e0 = tok_e[tok * 2], e1 = tok_e[tok * 2 + 1];
    bool m = (e0 == e) || (e1 == e);
    unsigned long long mask = __ballot(m);
    int pos = run + __popcll(mask & ((1ull << lane) - 1ull));
    if (m) {
      int gs = off + pos;
      list_tok[gs] = tok;
      tok_gslot[tok * 2 + ((e0 == e) ? 0 : 1)] = gs;
    }
    run += __popcll(mask);
  }
  const int cnt = cnts[e];
  const int padded = (cnt + 127) & ~127;
  for (int p = cnt + lane; p < padded; p += 64) list_tok[off + p] = 0;
}

// ---------------- grouped GEMM: 128x128 tile, BK=32, ring-3 LDS, counted vmcnt ----------------
// Round-8 verified core (chunk-XOR swizzle, 0 bank conflicts). TCONV: blocks past the
// GEMM grid run wave-private W2 transposes (4 waves x 64x32 tiles per block, barrier-free,
// nontemporal fp32 reads). Tail placement measured optimal (vs first/interleaved).
// FIRST: out = bf16 h with bias+GELU; else: out = bf16 partials[ks][row][col] (no bias).
template <int KTOT, int NTOT, bool FIRST, int NSPLIT, bool TCONV>
__global__ __launch_bounds__(256, 3) void moe_gemm(const unsigned short* __restrict__ Abase,
                                                   const unsigned short* __restrict__ Bbase,
                                                   const float* __restrict__ bias,
                                                   const int* __restrict__ list_tok,
                                                   const int* __restrict__ offs,
                                                   void* __restrict__ outp,
                                                   const float* __restrict__ W2f,
                                                   unsigned short* __restrict__ w2t) {
  constexpr int KS = KTOT / NSPLIT;   // K elems per slice
  constexpr int NT = KS / 32;         // K-steps (BK=32)
  constexpr int nM = MAXROWS / 128;
  constexpr int nN = NTOT / 128;
  constexpr int NWG_GEMM = nN * nM * NSPLIT;
  // ring of 3 slots, each: A[128][32] + B[128][32] bf16 = 16KB -> 48KB total
  __shared__ __align__(16) unsigned short lds[3][2][4096];

  const int tid = threadIdx.x;
  const int wave = tid >> 6, lane = tid & 63;

  if (TCONV && (int)blockIdx.x >= NWG_GEMM) {
    // W2 [E][I][H] -> w2t [E][H][I]; 4 wave-tiles per block; scratch 2368 floats/wave
    wave_tconv2(W2f, w2t, ((int)blockIdx.x - NWG_GEMM) * 4 + wave,
                (float*)&lds[0][0][0] + wave * (64 * 37), lane);
    return;
  }

  int wg = blockIdx.x;
  wg = (wg & 7) * (NWG_GEMM >> 3) + (wg >> 3);   // bijective XCD swizzle (NWG_GEMM % 8 == 0)
  const int ks = (NSPLIT > 1) ? (wg / (nM * nN)) : 0;
  const int rem = wg % (nM * nN);
  const int mt = rem % nM;                  // m fastest: neighbors share B panel in L2
  const int nt = rem / nM;
  const int grow0 = mt * 128;
  if (grow0 >= offs[NE]) return;
  int e = 0;
#pragma unroll
  for (int i = 1; i < NE; ++i) if (grow0 >= offs[i]) e = i;
  const int n0 = nt * 128;
  const int k0 = ks * KS;

  // --- staging sources: thread covers rows tid/4 + {0,64}; source chunk pre-swizzled ---
  const int srow = tid >> 2;
  const int skc = (((tid & 3) ^ ((srow >> 1) & 3)) * 8);  // chunk XOR swizzle, shorts
  const unsigned short* ag[2];
  const unsigned short* bg[2];
#pragma unroll
  for (int j = 0; j < 2; ++j) {
    const int row = srow + j * 64;   // (row>>1)&3 identical for j=0,1 (bit6 untouched)
    size_t arow;
    if (FIRST) arow = (size_t)list_tok[grow0 + row] * KTOT;
    else       arow = (size_t)(grow0 + row) * KTOT;
    ag[j] = Abase + arow + k0 + skc;
    bg[j] = Bbase + (size_t)e * NTOT * KTOT + (size_t)(n0 + row) * KTOT + k0 + skc;
  }
  // gld16 LDS dest must be WAVE-UNIFORM base (HW adds lane*16B)
  const int wbase = wave * 512;  // shorts: wave*1024B

  // --- fragment read offsets (shorts), swizzle folded in ---
  const int wm = wave >> 1, wn = wave & 1;
  const int fr = lane & 15;
  const int q = lane >> 4;       // 16B chunk index within the 64B row
  int aoff[4], boff[4];
#pragma unroll
  for (int m = 0; m < 4; ++m) {
    const int row = wm * 64 + m * 16 + fr;
    aoff[m] = row * 32 + ((q ^ ((row >> 1) & 3)) * 8);
  }
#pragma unroll
  for (int n = 0; n < 4; ++n) {
    const int row = wn * 64 + n * 16 + fr;
    boff[n] = row * 32 + ((q ^ ((row >> 1) & 3)) * 8);
  }

  f32x4 acc[4][4] = {};

#define STAGE(S, SLOT)                                             \
  {                                                                \
    gld16(ag[0] + (S) * 32, &lds[SLOT][0][wbase]);                 \
    gld16(ag[1] + (S) * 32, &lds[SLOT][0][wbase + 2048]);          \
    gld16(bg[0] + (S) * 32, &lds[SLOT][1][wbase]);                 \
    gld16(bg[1] + (S) * 32, &lds[SLOT][1][wbase + 2048]);          \
  }

#define KITER(S, SL, DO_STAGE, VMSTR)                                 \
  {                                                                   \
    asm volatile("s_waitcnt vmcnt(" VMSTR ")" ::: "memory");          \
    asm volatile("s_barrier" ::: "memory");                           \
    const unsigned short* A = &lds[SL][0][0];                         \
    const unsigned short* B = &lds[SL][1][0];                         \
    short8v af[4], bf[4];                                             \
    _Pragma("unroll")                                                 \
    for (int m = 0; m < 4; ++m) af[m] = *(const short8v*)&A[aoff[m]]; \
    _Pragma("unroll")                                                 \
    for (int n = 0; n < 4; ++n) bf[n] = *(const short8v*)&B[boff[n]]; \
    if (DO_STAGE) {                                                   \
      int s2 = (SL) + 2; if (s2 >= 3) s2 -= 3;                        \
      STAGE((S) + 2, s2);                                             \
    }                                                                 \
    __builtin_amdgcn_s_setprio(1);                                    \
    _Pragma("unroll")                                                 \
    for (int n = 0; n < 4; ++n)                                       \
      _Pragma("unroll")                                               \
      for (int m = 0; m < 4; ++m)                                     \
        acc[m][n] = __builtin_amdgcn_mfma_f32_16x16x32_bf16(af[m], bf[n], acc[m][n], 0, 0, 0); \
    __builtin_amdgcn_s_setprio(0);                                    \
  }

  // prologue: stage steps 0,1 into slots 0,1 (8 loads outstanding)
  STAGE(0, 0);
  STAGE(1, 1);

  int sl = 0;
  for (int s = 0; s < NT - 2; ++s) {
    KITER(s, sl, true, "4");
    sl = sl + 1; if (sl >= 3) sl = 0;
  }
  KITER(NT - 2, sl, false, "4");
  sl = sl + 1; if (sl >= 3) sl = 0;
  KITER(NT - 1, sl, false, "0");

#undef KITER
#undef STAGE

  const int r4 = lane >> 4;
#pragma unroll
  for (int m = 0; m < 4; ++m) {
#pragma unroll
    for (int n = 0; n < 4; ++n) {
      const int gcol = n0 + wn * 64 + n * 16 + fr;
      float bv = 0.f;
      if (FIRST) bv = bias[e * NTOT + gcol];
#pragma unroll
      for (int r = 0; r < 4; ++r) {
        const int grow = grow0 + wm * 64 + m * 16 + r4 * 4 + r;
        float v = acc[m][n][r] + bv;
        if (FIRST) {
          v = 0.5f * v * (1.0f + erff(v * 0.70710678118654752f));
          ((unsigned short*)outp)[(size_t)grow * NTOT + gcol] = f2bf(v);
        } else {
          // bf16 partial (no bias; reduced in combine)
          ((unsigned short*)outp)[((size_t)ks * MAXROWS + grow) * NTOT + gcol] = f2bf(v);
        }
      }
    }
  }
}

// -------- combine: y[t] = w0*(sum_ks p16[ks][gs0]+b2[e0]) + w1*(...)  (4 bf16 slices) --------
template <int NSPLIT>
__global__ __launch_bounds__(256) void combine_kernel(const unsigned short* __restrict__ part,
                                                      const int* __restrict__ tok_gslot,
                                                      const int* __restrict__ tok_e,
                                                      const float* __restrict__ tok_w,
                                                      const float* __restrict__ b2,
                                                      float* __restrict__ y) {
  const int t = blockIdx.x;
  const int c = threadIdx.x * 4;
  const int gs0 = tok_gslot[t * 2 + 0], gs1 = tok_gslot[t * 2 + 1];
  const int e0 = tok_e[t * 2 + 0], e1 = tok_e[t * 2 + 1];
  const float w0 = tok_w[t * 2 + 0], w1 = tok_w[t * 2 + 1];
  float s0[4] = {0.f, 0.f, 0.f, 0.f}, s1[4] = {0.f, 0.f, 0.f, 0.f};
#pragma unroll
  for (int ks = 0; ks < NSPLIT; ++ks) {
    short4v p0 = *(const short4v*)&part[((size_t)ks * MAXROWS + gs0) * HID + c];
    short4v p1 = *(const short4v*)&part[((size_t)ks * MAXROWS + gs1) * HID + c];
#pragma unroll
    for (int i = 0; i < 4; ++i) {
      s0[i] += bf2f((unsigned short)p0[i]);
      s1[i] += bf2f((unsigned short)p1[i]);
    }
  }
  f32x4 bb0 = *(const f32x4*)&b2[e0 * HID + c];
  f32x4 bb1 = *(const f32x4*)&b2[e1 * HID + c];
  f32x4 r;
#pragma unroll
  for (int i = 0; i < 4; ++i)
    r[i] = w0 * (s0[i] + bb0[i]) + w1 * (s1[i] + bb1[i]);
  *(f32x4*)&y[(size_t)t * HID + c] = r;
}

extern "C" void kernel_launch(void* const* d_in, const int* in_sizes, int n_in,
                              void* d_out, int out_size, void* d_ws, size_t ws_size,
                              hipStream_t stream) {
  const float* x  = (const float*)d_in[0];
  const float* wg = (const float*)d_in[1];
  const float* W1 = (const float*)d_in[2];
  const float* b1 = (const float*)d_in[3];
  const float* W2 = (const float*)d_in[4];
  const float* b2 = (const float*)d_in[5];
  float* y = (float*)d_out;

  unsigned char* ws = (unsigned char*)d_ws;
  size_t off = 0;
  // w1t (live prep->gemm1) aliases part (bf16, 4 slices x 10.5MB = 42MB, live gemm2->combine)
  unsigned short* w1t  = (unsigned short*)(ws + off);
  unsigned short* part = (unsigned short*)(ws + off); off += (size_t)NE * HID * INTER * 2;  // 67MB
  unsigned short* w2t  = (unsigned short*)(ws + off); off += (size_t)NE * INTER * HID * 2;  // 67MB
  unsigned short* xb   = (unsigned short*)(ws + off); off += (size_t)NTOK * HID * 2;        // 4MB
  unsigned short* h    = (unsigned short*)(ws + off); off += (size_t)MAXROWS * INTER * 2;   // 42MB
  int* tok_e           = (int*)(ws + off);            off += NTOK * 2 * 4;
  float* tok_w         = (float*)(ws + off);          off += NTOK * 2 * 4;
  int* tok_gslot       = (int*)(ws + off);            off += NTOK * 2 * 4;
  int* list_tok        = (int*)(ws + off);            off += MAXROWS * 4;
  int* offs            = (int*)(ws + off);            off += 64;
  (void)ws_size; (void)in_sizes; (void)n_in; (void)out_size;

  // prep: convx (2048) + tconv1 (8192) + gating (2048) -- all independent
  prep_kernel<<<2048 + 8192 + 2048, 256, 0, stream>>>(x, W1, wg, xb, w1t, tok_e, tok_w);
  routing_kernel<<<1, 512, 0, stream>>>(tok_e, list_tok, tok_gslot, offs);
  // GEMM1 (1280 blocks) + 4096 wave-tconv2 filler blocks (16384 wave-tiles / 4 waves)
  moe_gemm<HID, INTER, true, 1, true>
      <<<(INTER / 128) * (MAXROWS / 128) + 4096, 256, 0, stream>>>(
          xb, w1t, b1, list_tok, offs, (void*)h, W2, w2t);
  moe_gemm<INTER, HID, false, 4, false>
      <<<(HID / 128) * (MAXROWS / 128) * 4, 256, 0, stream>>>(
          h, w2t, b2, list_tok, offs, (void*)part, nullptr, nullptr);
  combine_kernel<4><<<NTOK, 256, 0, stream>>>(part, tok_gslot, tok_e, tok_w, b2, y);
}